// Round 1
// baseline (46.106 us; speedup 1.0000x reference)
//
#include <hip/hip_runtime.h>
#include <hip/hip_bf16.h>

#define TOKENS 32
#define KDIM   4096
#define NDIM   11008
#define GSZ    64
#define KP     (KDIM/2)     // qweight cols (int32), 2048
#define NGRP   (KDIM/GSZ)   // 64 groups

typedef float  f32x4 __attribute__((ext_vector_type(4)));
typedef int    i32x4 __attribute__((ext_vector_type(4)));
typedef short  s16x8 __attribute__((ext_vector_type(8)));

// Prologue: x f32 -> bf16 (bit pattern in shorts) into ws. 131072 elems, 8/thread.
__global__ void cvt_x_kernel(const float* __restrict__ x, s16x8* __restrict__ xb) {
    int i = blockIdx.x * blockDim.x + threadIdx.x;   // 16384 threads
    const f32x4* xv = reinterpret_cast<const f32x4*>(x);
    f32x4 v0 = xv[2 * i], v1 = xv[2 * i + 1];
    s16x8 o;
#pragma unroll
    for (int e = 0; e < 4; ++e) {
        o[e]     = __builtin_bit_cast(short, __float2bfloat16(v0[e]));
        o[e + 4] = __builtin_bit_cast(short, __float2bfloat16(v1[e]));
    }
    xb[i] = o;
}

// Each wave: 16 output cols x full K. MFMA 16x16x32 bf16, 2 M-tiles (32 tokens).
// B frag: lane holds col n = base + (lane&15), k = (lane>>4)*8 + e (e=0..7).
// Those 8 k live in nibbles {2j,2j+1} (j=n&3) of 4 consecutive int32s of qweight
// row n>>2 -> one dwordx4 per lane per K=32 chunk.
template <int USE_XB>
__global__ __launch_bounds__(128) void awq_gemm_kernel(
    const int* __restrict__ qw, const float* __restrict__ sc,
    const float* __restrict__ zp, const float* __restrict__ bias,
    const float* __restrict__ xf, const unsigned short* __restrict__ xb,
    float* __restrict__ out) {
    const int lane = threadIdx.x & 63;
    const int wave = threadIdx.x >> 6;
    const int col  = lane & 15;
    const int kg   = lane >> 4;                   // k-group 0..3
    const int n    = blockIdx.x * 32 + wave * 16 + col;
    const int j    = n & 3;
    const int qrow = n >> 2;
    const int sh0  = 8 * j;                       // nibble 2j at bit 4*(2j)

    const int* qp = qw + qrow * KP + kg * 4;
    const int r0 = col, r1 = col + 16;            // token rows for the 2 M-tiles

    f32x4 acc0 = {0.f, 0.f, 0.f, 0.f};
    f32x4 acc1 = {0.f, 0.f, 0.f, 0.f};

    for (int g = 0; g < NGRP; ++g) {
        const float s = sc[g * NDIM + n];
        const float b = -zp[g * NDIM + n] * s;    // w = q*s + b
#pragma unroll
        for (int h = 0; h < 2; ++h) {
            const int chunk = 2 * g + h;          // K=32 chunk index
            i32x4 q = *reinterpret_cast<const i32x4*>(qp + chunk * 16);

            s16x8 a0, a1;
            if (USE_XB) {
                a0 = *reinterpret_cast<const s16x8*>(xb + r0 * KDIM + chunk * 32 + kg * 8);
                a1 = *reinterpret_cast<const s16x8*>(xb + r1 * KDIM + chunk * 32 + kg * 8);
            } else {
                const float* p0 = xf + r0 * KDIM + chunk * 32 + kg * 8;
                const float* p1 = xf + r1 * KDIM + chunk * 32 + kg * 8;
                f32x4 u0 = *reinterpret_cast<const f32x4*>(p0);
                f32x4 u1 = *reinterpret_cast<const f32x4*>(p0 + 4);
                f32x4 u2 = *reinterpret_cast<const f32x4*>(p1);
                f32x4 u3 = *reinterpret_cast<const f32x4*>(p1 + 4);
#pragma unroll
                for (int e = 0; e < 4; ++e) {
                    a0[e]     = __builtin_bit_cast(short, __float2bfloat16(u0[e]));
                    a0[e + 4] = __builtin_bit_cast(short, __float2bfloat16(u1[e]));
                    a1[e]     = __builtin_bit_cast(short, __float2bfloat16(u2[e]));
                    a1[e + 4] = __builtin_bit_cast(short, __float2bfloat16(u3[e]));
                }
            }

            s16x8 wf;
#pragma unroll
            for (int d = 0; d < 4; ++d) {
                const int qd = q[d];
                float w0 = (float)((qd >> sh0) & 15);        // k = chunk*32+kg*8+2d
                float w1 = (float)((qd >> (sh0 + 4)) & 15);  // k = ... + 2d+1
                w0 = w0 * s + b;
                w1 = w1 * s + b;
                wf[2 * d]     = __builtin_bit_cast(short, __float2bfloat16(w0));
                wf[2 * d + 1] = __builtin_bit_cast(short, __float2bfloat16(w1));
            }

            acc0 = __builtin_amdgcn_mfma_f32_16x16x32_bf16(a0, wf, acc0, 0, 0, 0);
            acc1 = __builtin_amdgcn_mfma_f32_16x16x32_bf16(a1, wf, acc1, 0, 0, 0);
        }
    }

    // D layout (verified m89/m91): col = lane&15, row = (lane>>4)*4 + r
    const float bv = bias[n];
#pragma unroll
    for (int r = 0; r < 4; ++r) {
        const int t = kg * 4 + r;
        out[t * NDIM + n]        = acc0[r] + bv;
        out[(t + 16) * NDIM + n] = acc1[r] + bv;
    }
}

extern "C" void kernel_launch(void* const* d_in, const int* in_sizes, int n_in,
                              void* d_out, int out_size, void* d_ws, size_t ws_size,
                              hipStream_t stream) {
    const float* x    = (const float*)d_in[0];
    const int*   qw   = (const int*)d_in[1];
    const float* sc   = (const float*)d_in[2];
    const float* zp   = (const float*)d_in[3];
    const float* bias = (const float*)d_in[4];
    float*       out  = (float*)d_out;

    const size_t xb_bytes = (size_t)TOKENS * KDIM * sizeof(unsigned short);
    if (ws_size >= xb_bytes) {
        unsigned short* xb = (unsigned short*)d_ws;
        cvt_x_kernel<<<64, 256, 0, stream>>>(x, (s16x8*)xb);
        awq_gemm_kernel<1><<<NDIM / 32, 128, 0, stream>>>(qw, sc, zp, bias, x, xb, out);
    } else {
        awq_gemm_kernel<0><<<NDIM / 32, 128, 0, stream>>>(qw, sc, zp, bias, x, nullptr, out);
    }
}

// Round 3
// 44.135 us; speedup vs baseline: 1.0447x; 1.0447x over previous
//
#include <hip/hip_runtime.h>
#include <hip/hip_bf16.h>

#define TOKENS 32
#define KDIM   4096
#define NDIM   11008
#define GSZ    64
#define KP     (KDIM/2)     // qweight cols (int32), 2048
#define NGRP   (KDIM/GSZ)   // 64 groups
#define KSEGS  4            // K-split factor (waves per col-tile)

typedef float  f32x4 __attribute__((ext_vector_type(4)));
typedef int    i32x4 __attribute__((ext_vector_type(4)));
typedef short  s16x8 __attribute__((ext_vector_type(8)));

// Prologue: x f32 -> bf16 (bit pattern in shorts) into ws. 131072 elems, 8/thread.
__global__ void cvt_x_kernel(const float* __restrict__ x, s16x8* __restrict__ xb) {
    int i = blockIdx.x * blockDim.x + threadIdx.x;   // 16384 threads
    const f32x4* xv = reinterpret_cast<const f32x4*>(x);
    f32x4 v0 = xv[2 * i], v1 = xv[2 * i + 1];
    s16x8 o;
#pragma unroll
    for (int e = 0; e < 4; ++e) {
        o[e]     = __builtin_bit_cast(short, __float2bfloat16(v0[e]));
        o[e + 4] = __builtin_bit_cast(short, __float2bfloat16(v1[e]));
    }
    xb[i] = o;
}

// Block = 512 threads = 8 waves = 2 col-tiles (16 cols each) x 4 K-segments.
// Each wave: MFMA 16x16x32 bf16, 2 M-tiles (32 tokens), 16 groups of K.
// B frag: lane holds col n = base + (lane&15), k = (lane>>4)*8 + e (e=0..7);
// those 8 k are nibbles {2j,2j+1} (j=n&3) of 4 consecutive int32s of qweight
// row n>>2 -> one dwordx4 per lane per K=32 chunk.
// K-partials reduced through LDS; kseg==0 waves write out + bias.
template <int USE_XB>
__global__ __launch_bounds__(512) void awq_gemm_kernel(
    const int* __restrict__ qw, const float* __restrict__ sc,
    const float* __restrict__ zp, const float* __restrict__ bias,
    const float* __restrict__ xf, const unsigned short* __restrict__ xb,
    float* __restrict__ out) {
    const int lane    = threadIdx.x & 63;
    const int wave    = threadIdx.x >> 6;     // 0..7
    const int colTile = wave & 1;             // 0..1
    const int kseg    = wave >> 1;            // 0..3
    const int col     = lane & 15;
    const int kg      = lane >> 4;            // k-group 0..3
    const int n       = blockIdx.x * 32 + colTile * 16 + col;
    const int j       = n & 3;
    const int qrow    = n >> 2;
    const int sh0     = 8 * j;                // nibble 2j at bit 4*(2j)

    const int* qp = qw + qrow * KP + kg * 4;
    const int r0 = col, r1 = col + 16;        // token rows for the 2 M-tiles

    f32x4 acc0 = {0.f, 0.f, 0.f, 0.f};
    f32x4 acc1 = {0.f, 0.f, 0.f, 0.f};

    const int g_lo = kseg * (NGRP / KSEGS);
    const int g_hi = g_lo + (NGRP / KSEGS);

#pragma unroll 2
    for (int g = g_lo; g < g_hi; ++g) {
        const float s = sc[g * NDIM + n];
        const float b = -zp[g * NDIM + n] * s;    // w = q*s + b
#pragma unroll
        for (int h = 0; h < 2; ++h) {
            const int chunk = 2 * g + h;          // K=32 chunk index
            i32x4 q = *reinterpret_cast<const i32x4*>(qp + chunk * 16);

            s16x8 a0, a1;
            if (USE_XB) {
                a0 = *reinterpret_cast<const s16x8*>(xb + r0 * KDIM + chunk * 32 + kg * 8);
                a1 = *reinterpret_cast<const s16x8*>(xb + r1 * KDIM + chunk * 32 + kg * 8);
            } else {
                const float* p0 = xf + r0 * KDIM + chunk * 32 + kg * 8;
                const float* p1 = xf + r1 * KDIM + chunk * 32 + kg * 8;
                f32x4 u0 = *reinterpret_cast<const f32x4*>(p0);
                f32x4 u1 = *reinterpret_cast<const f32x4*>(p0 + 4);
                f32x4 u2 = *reinterpret_cast<const f32x4*>(p1);
                f32x4 u3 = *reinterpret_cast<const f32x4*>(p1 + 4);
#pragma unroll
                for (int e = 0; e < 4; ++e) {
                    a0[e]     = __builtin_bit_cast(short, __float2bfloat16(u0[e]));
                    a0[e + 4] = __builtin_bit_cast(short, __float2bfloat16(u1[e]));
                    a1[e]     = __builtin_bit_cast(short, __float2bfloat16(u2[e]));
                    a1[e + 4] = __builtin_bit_cast(short, __float2bfloat16(u3[e]));
                }
            }

            s16x8 wf;
#pragma unroll
            for (int d = 0; d < 4; ++d) {
                const int qd = q[d];
                float w0 = (float)((qd >> sh0) & 15);        // k = chunk*32+kg*8+2d
                float w1 = (float)((qd >> (sh0 + 4)) & 15);  // k = ... + 2d+1
                w0 = w0 * s + b;
                w1 = w1 * s + b;
                wf[2 * d]     = __builtin_bit_cast(short, __float2bfloat16(w0));
                wf[2 * d + 1] = __builtin_bit_cast(short, __float2bfloat16(w1));
            }

            acc0 = __builtin_amdgcn_mfma_f32_16x16x32_bf16(a0, wf, acc0, 0, 0, 0);
            acc1 = __builtin_amdgcn_mfma_f32_16x16x32_bf16(a1, wf, acc1, 0, 0, 0);
        }
    }

    // Reduce K-segments through LDS: slots for kseg 1..3, both col-tiles.
    __shared__ float red[(KSEGS - 1) * 2][64][8];   // 12 KB
    if (kseg != 0) {
        const int slot = (kseg - 1) * 2 + colTile;
#pragma unroll
        for (int e = 0; e < 4; ++e) {
            red[slot][lane][e]     = acc0[e];
            red[slot][lane][4 + e] = acc1[e];
        }
    }
    __syncthreads();
    if (kseg == 0) {
#pragma unroll
        for (int sseg = 0; sseg < KSEGS - 1; ++sseg) {
            const int slot = sseg * 2 + colTile;
#pragma unroll
            for (int e = 0; e < 4; ++e) {
                acc0[e] += red[slot][lane][e];
                acc1[e] += red[slot][lane][4 + e];
            }
        }
        // D layout (verified m89/m91): col = lane&15, row = (lane>>4)*4 + r
        const float bv = bias[n];
#pragma unroll
        for (int r = 0; r < 4; ++r) {
            const int t = kg * 4 + r;
            out[t * NDIM + n]        = acc0[r] + bv;
            out[(t + 16) * NDIM + n] = acc1[r] + bv;
        }
    }
}

extern "C" void kernel_launch(void* const* d_in, const int* in_sizes, int n_in,
                              void* d_out, int out_size, void* d_ws, size_t ws_size,
                              hipStream_t stream) {
    const float* x    = (const float*)d_in[0];
    const int*   qw   = (const int*)d_in[1];
    const float* sc   = (const float*)d_in[2];
    const float* zp   = (const float*)d_in[3];
    const float* bias = (const float*)d_in[4];
    float*       out  = (float*)d_out;

    const size_t xb_bytes = (size_t)TOKENS * KDIM * sizeof(unsigned short);
    if (ws_size >= xb_bytes) {
        unsigned short* xb = (unsigned short*)d_ws;
        cvt_x_kernel<<<64, 256, 0, stream>>>(x, (s16x8*)xb);
        awq_gemm_kernel<1><<<NDIM / 32, 512, 0, stream>>>(qw, sc, zp, bias, x, xb, out);
    } else {
        awq_gemm_kernel<0><<<NDIM / 32, 512, 0, stream>>>(qw, sc, zp, bias, x, nullptr, out);
    }
}

// Round 7
// 37.142 us; speedup vs baseline: 1.2414x; 1.1883x over previous
//
#include <hip/hip_runtime.h>
#include <hip/hip_bf16.h>

#define TOKENS 32
#define KDIM   4096
#define NDIM   11008
#define GSZ    64
#define KP     (KDIM/2)     // qweight cols (int32), 2048
#define NGRP   (KDIM/GSZ)   // 64 groups
#define KSEGS  4            // K-split factor (waves per block)

typedef float  f32x4 __attribute__((ext_vector_type(4)));
typedef int    i32x4 __attribute__((ext_vector_type(4)));
typedef short  s16x8 __attribute__((ext_vector_type(8)));

// Prologue: x f32 -> bf16 (bit pattern in shorts) into ws. 131072 elems, 8/thread.
__global__ void cvt_x_kernel(const float* __restrict__ x, s16x8* __restrict__ xb) {
    int i = blockIdx.x * blockDim.x + threadIdx.x;   // 16384 threads
    const f32x4* xv = reinterpret_cast<const f32x4*>(x);
    f32x4 v0 = xv[2 * i], v1 = xv[2 * i + 1];
    s16x8 o;
#pragma unroll
    for (int e = 0; e < 4; ++e) {
        o[e]     = __builtin_bit_cast(short, __float2bfloat16(v0[e]));
        o[e + 4] = __builtin_bit_cast(short, __float2bfloat16(v1[e]));
    }
    xb[i] = o;
}

// Block = 256 threads = 4 waves = 1 col-tile (16 cols) x 4 K-segments.
// Wave: 16 groups of K, explicit 4-deep software pipeline (gA..gD buffers).
// B frag: lane holds col n = base + (lane&15), k = (lane>>4)*8 + e (e=0..7);
// nibbles {2j,2j+1} (j=n&3) of 4 consecutive int32s of qweight row n>>2.
// Dequant EXACT: (float)((q>>sh)&15) * s + (-z*s).  (Magic-offset trick removed:
// folding 2^23 into the bias loses ~s/2 per group -> absmax 0.34 > 0.309.)
// K-partials reduced through LDS; kseg==0 wave writes out + bias.
template <int USE_XB>
__global__ __launch_bounds__(256, 3) void awq_gemm_kernel(
    const int* __restrict__ qw, const float* __restrict__ sc,
    const float* __restrict__ zp, const float* __restrict__ bias,
    const float* __restrict__ xf, const unsigned short* __restrict__ xb,
    float* __restrict__ out) {
    const int lane = threadIdx.x & 63;
    const int kseg = threadIdx.x >> 6;        // 0..3
    const int col  = lane & 15;
    const int kg   = lane >> 4;               // k-group 0..3
    const int n    = blockIdx.x * 16 + col;
    const int j    = n & 3;
    const int qrow = n >> 2;
    const int sh0  = 8 * j;                   // nibble 2j at bit 4*(2j)

    const int* qp = qw + qrow * KP + kg * 4;
    const int r0 = col, r1 = col + 16;        // token rows for the 2 M-tiles

    f32x4 acc0 = {0.f, 0.f, 0.f, 0.f};
    f32x4 acc1 = {0.f, 0.f, 0.f, 0.f};

    struct GData { float s, z; i32x4 q0, q1; s16x8 a00, a01, a10, a11; };

    auto cvt8 = [](const float* p) {
        f32x4 u0 = *reinterpret_cast<const f32x4*>(p);
        f32x4 u1 = *reinterpret_cast<const f32x4*>(p + 4);
        s16x8 o;
#pragma unroll
        for (int e = 0; e < 4; ++e) {
            o[e]     = __builtin_bit_cast(short, __float2bfloat16(u0[e]));
            o[e + 4] = __builtin_bit_cast(short, __float2bfloat16(u1[e]));
        }
        return o;
    };

    auto LOAD = [&](GData& d, int g) {
        g = g < NGRP ? g : NGRP - 1;          // clamp prefetch overhang
        d.s = sc[g * NDIM + n];
        d.z = zp[g * NDIM + n];
        const int* q = qp + g * 32;           // chunk 2g at qp + (2g)*16
        d.q0 = *reinterpret_cast<const i32x4*>(q);
        d.q1 = *reinterpret_cast<const i32x4*>(q + 16);
        if (USE_XB) {
            const unsigned short* xa = xb + g * GSZ + kg * 8;
            d.a00 = *reinterpret_cast<const s16x8*>(xa + r0 * KDIM);
            d.a10 = *reinterpret_cast<const s16x8*>(xa + r0 * KDIM + 32);
            d.a01 = *reinterpret_cast<const s16x8*>(xa + r1 * KDIM);
            d.a11 = *reinterpret_cast<const s16x8*>(xa + r1 * KDIM + 32);
        } else {
            const float* xa = xf + g * GSZ + kg * 8;
            d.a00 = cvt8(xa + r0 * KDIM);
            d.a10 = cvt8(xa + r0 * KDIM + 32);
            d.a01 = cvt8(xa + r1 * KDIM);
            d.a11 = cvt8(xa + r1 * KDIM + 32);
        }
    };

    auto COMPUTE = [&](const GData& d) {
        const float s  = d.s;
        const float bz = -d.z * s;            // w = q*s + bz (exact path)
#pragma unroll
        for (int c = 0; c < 2; ++c) {
            const i32x4 q = c ? d.q1 : d.q0;
            s16x8 wf;
#pragma unroll
            for (int dd = 0; dd < 4; ++dd) {
                const int qd = q[dd];
                float w0 = (float)((qd >> sh0) & 15) * s + bz;
                float w1 = (float)((qd >> (sh0 + 4)) & 15) * s + bz;
                wf[2 * dd]     = __builtin_bit_cast(short, __float2bfloat16(w0));
                wf[2 * dd + 1] = __builtin_bit_cast(short, __float2bfloat16(w1));
            }
            if (c == 0) {
                acc0 = __builtin_amdgcn_mfma_f32_16x16x32_bf16(d.a00, wf, acc0, 0, 0, 0);
                acc1 = __builtin_amdgcn_mfma_f32_16x16x32_bf16(d.a01, wf, acc1, 0, 0, 0);
            } else {
                acc0 = __builtin_amdgcn_mfma_f32_16x16x32_bf16(d.a10, wf, acc0, 0, 0, 0);
                acc1 = __builtin_amdgcn_mfma_f32_16x16x32_bf16(d.a11, wf, acc1, 0, 0, 0);
            }
        }
    };

    const int g_lo = kseg * (NGRP / KSEGS);
    const int g_hi = g_lo + (NGRP / KSEGS);   // 16 groups per wave

    GData gA, gB, gC, gD;
    LOAD(gA, g_lo);
    LOAD(gB, g_lo + 1);
    LOAD(gC, g_lo + 2);
    LOAD(gD, g_lo + 3);

    for (int g = g_lo; g < g_hi; g += 4) {
        COMPUTE(gA); LOAD(gA, g + 4);
        COMPUTE(gB); LOAD(gB, g + 5);
        COMPUTE(gC); LOAD(gC, g + 6);
        COMPUTE(gD); LOAD(gD, g + 7);
    }

    // Reduce K-segments through LDS (padded to 9 floats -> no 8-way bank conflict).
    __shared__ float red[KSEGS - 1][64][9];
    if (kseg != 0) {
#pragma unroll
        for (int e = 0; e < 4; ++e) {
            red[kseg - 1][lane][e]     = acc0[e];
            red[kseg - 1][lane][4 + e] = acc1[e];
        }
    }
    __syncthreads();
    if (kseg == 0) {
#pragma unroll
        for (int sseg = 0; sseg < KSEGS - 1; ++sseg) {
#pragma unroll
            for (int e = 0; e < 4; ++e) {
                acc0[e] += red[sseg][lane][e];
                acc1[e] += red[sseg][lane][4 + e];
            }
        }
        // D layout (verified m89/m91): col = lane&15, row = (lane>>4)*4 + r
        const float bv = bias[n];
#pragma unroll
        for (int r = 0; r < 4; ++r) {
            const int t = kg * 4 + r;
            out[t * NDIM + n]        = acc0[r] + bv;
            out[(t + 16) * NDIM + n] = acc1[r] + bv;
        }
    }
}

extern "C" void kernel_launch(void* const* d_in, const int* in_sizes, int n_in,
                              void* d_out, int out_size, void* d_ws, size_t ws_size,
                              hipStream_t stream) {
    const float* x    = (const float*)d_in[0];
    const int*   qw   = (const int*)d_in[1];
    const float* sc   = (const float*)d_in[2];
    const float* zp   = (const float*)d_in[3];
    const float* bias = (const float*)d_in[4];
    float*       out  = (float*)d_out;

    const size_t xb_bytes = (size_t)TOKENS * KDIM * sizeof(unsigned short);
    if (ws_size >= xb_bytes) {
        unsigned short* xb = (unsigned short*)d_ws;
        cvt_x_kernel<<<64, 256, 0, stream>>>(x, (s16x8*)xb);
        awq_gemm_kernel<1><<<NDIM / 16, 256, 0, stream>>>(qw, sc, zp, bias, x, xb, out);
    } else {
        awq_gemm_kernel<0><<<NDIM / 16, 256, 0, stream>>>(qw, sc, zp, bias, x, nullptr, out);
    }
}

// Round 9
// 25.439 us; speedup vs baseline: 1.8124x; 1.4600x over previous
//
#include <hip/hip_runtime.h>
#include <hip/hip_bf16.h>

#define TOKENS 32
#define KDIM   4096
#define NDIM   11008
#define GSZ    64
#define KP     (KDIM/2)          // qweight row length in int32 (2048)
#define NGRP   (KDIM/GSZ)        // 64 groups
#define OUTK   8                 // K-splits across blocks (ws partials)
#define INK    2                 // K-splits inside block (LDS reduction)
#define BLK_COLS 128             // 4 colWaves * 32 cols
#define NBLK_C (NDIM/BLK_COLS)   // 86
#define KSLICE (KDIM/OUTK)       // 512 k per block
#define GPW    (KSLICE/INK/GSZ)  // 4 groups per wave
#define PART_ELEMS (TOKENS*NDIM) // 352256

typedef float  f32x4 __attribute__((ext_vector_type(4)));
typedef int    i32x4 __attribute__((ext_vector_type(4)));
typedef short  s16x8 __attribute__((ext_vector_type(8)));

// Prologue: x f32 -> bf16 into ws[0:256KB). 131072 elems, 8/thread.
__global__ void cvt_x_kernel(const float* __restrict__ x, s16x8* __restrict__ xb) {
    int i = blockIdx.x * blockDim.x + threadIdx.x;   // 16384 threads
    const f32x4* xv = reinterpret_cast<const f32x4*>(x);
    f32x4 v0 = xv[2 * i], v1 = xv[2 * i + 1];
    s16x8 o;
#pragma unroll
    for (int e = 0; e < 4; ++e) {
        o[e]     = __builtin_bit_cast(short, __float2bfloat16(v0[e]));
        o[e + 4] = __builtin_bit_cast(short, __float2bfloat16(v1[e]));
    }
    xb[i] = o;
}

// Main GEMM: grid = 86 colGroups x 8 outer-ksegs = 688 blocks, 512 thr = 8 waves.
// Wave = (colWave cw 0..3: 32 cols via 2 B-frags) x (inner kseg ks 0..1).
// Block stages x K-slice (32 tok x 512 k bf16 = 32KB) in LDS, XOR-swizzled:
// stored byte = lin ^ ((tok&7)<<4); reads apply the SAME xor to the full
// in-row offset (round-8 bug: xor applied only to kg field, carried into the
// c field and overran xs -> NaN).
// Each wave: 4 groups; q/s/z software-pipelined 2-deep; 8 MFMA per group.
// Inner ksegs reduced via LDS; result written as f32 partial[outer][32][11008].
__global__ __launch_bounds__(512, 2) void awq_gemm2(
    const int* __restrict__ qw, const float* __restrict__ sc,
    const float* __restrict__ zp, const unsigned short* __restrict__ xb,
    float* __restrict__ partial) {
    __shared__ unsigned short xs[TOKENS * KSLICE];   // 32 KB
    __shared__ float red[4][64][17];                 // 17.4 KB

    const int tid  = threadIdx.x;
    const int lane = tid & 63;
    const int wid  = tid >> 6;       // 0..7
    const int cw   = wid & 3;        // colWave
    const int ks   = wid >> 2;       // inner kseg 0..1
    const int bc   = blockIdx.x % NBLK_C;
    const int ob   = blockIdx.x / NBLK_C;
    const int K0   = ob * KSLICE;

    // ---- stage x slice into LDS (wave i writes token-row i per iter, coalesced) ----
#pragma unroll
    for (int it = 0; it < 4; ++it) {
        const int lin  = it * 8192 + tid * 16;       // byte offset in slice
        const int tok  = lin >> 10;
        const int kloc = (lin & 1023) >> 1;
        s16x8 v = *reinterpret_cast<const s16x8*>(xb + tok * KDIM + K0 + kloc);
        *reinterpret_cast<s16x8*>(
            reinterpret_cast<char*>(xs) + (lin ^ ((tok & 7) << 4))) = v;
    }
    __syncthreads();

    const int col  = lane & 15;
    const int kg   = lane >> 4;                      // k-subgroup 0..3
    const int n0   = bc * BLK_COLS + cw * 32 + col;  // colset-0 column
    const int sh0  = 8 * (n0 & 3);
    const int qrow0 = n0 >> 2;
    const int* qp0 = qw + qrow0 * KP + kg * 4;       // colset-1 = +4*KP ints

    f32x4 acc00 = {0,0,0,0}, acc01 = {0,0,0,0};      // [colset][Mtile]
    f32x4 acc10 = {0,0,0,0}, acc11 = {0,0,0,0};

    struct GD { float s0, z0, s1, z1; i32x4 qa0, qa1, qb0, qb1; };

    auto LOADG = [&](GD& d, int gl) {
        gl = gl < GPW ? gl : GPW - 1;                // clamp prefetch overhang
        const int gg = ob * (NGRP / OUTK) + ks * GPW + gl;  // global group
        d.s0 = sc[gg * NDIM + n0];        d.z0 = zp[gg * NDIM + n0];
        d.s1 = sc[gg * NDIM + n0 + 16];   d.z1 = zp[gg * NDIM + n0 + 16];
        const int* q = qp0 + gg * 32;
        d.qa0 = *reinterpret_cast<const i32x4*>(q);
        d.qa1 = *reinterpret_cast<const i32x4*>(q + 16);
        d.qb0 = *reinterpret_cast<const i32x4*>(q + 4 * KP);
        d.qb1 = *reinterpret_cast<const i32x4*>(q + 4 * KP + 16);
    };

    auto LDSA = [&](int tok, int c) -> s16x8 {       // a-frag from swizzled LDS
        const int inrow = ((c << 6) + (kg << 4)) ^ ((tok & 7) << 4);
        return *reinterpret_cast<const s16x8*>(
            reinterpret_cast<const char*>(xs) + (tok << 10) + inrow);
    };

    auto DQ = [&](const i32x4& q, float s, float bz) -> s16x8 {
        s16x8 wf;
#pragma unroll
        for (int dd = 0; dd < 4; ++dd) {
            const int qd = q[dd];
            float w0 = (float)((qd >> sh0) & 15) * s + bz;        // exact dequant
            float w1 = (float)((qd >> (sh0 + 4)) & 15) * s + bz;
            wf[2 * dd]     = __builtin_bit_cast(short, __float2bfloat16(w0));
            wf[2 * dd + 1] = __builtin_bit_cast(short, __float2bfloat16(w1));
        }
        return wf;
    };

    auto COMPUTE = [&](const GD& d, int gl) {
        const int c0 = ks * 8 + gl * 2;              // local K32-chunk
        s16x8 a00 = LDSA(col, c0),      a01 = LDSA(col + 16, c0);
        s16x8 a10 = LDSA(col, c0 + 1),  a11 = LDSA(col + 16, c0 + 1);
        const float bz0 = -d.z0 * d.s0, bz1 = -d.z1 * d.s1;
        s16x8 w00 = DQ(d.qa0, d.s0, bz0), w01 = DQ(d.qa1, d.s0, bz0);
        s16x8 w10 = DQ(d.qb0, d.s1, bz1), w11 = DQ(d.qb1, d.s1, bz1);
        acc00 = __builtin_amdgcn_mfma_f32_16x16x32_bf16(a00, w00, acc00, 0, 0, 0);
        acc01 = __builtin_amdgcn_mfma_f32_16x16x32_bf16(a01, w00, acc01, 0, 0, 0);
        acc10 = __builtin_amdgcn_mfma_f32_16x16x32_bf16(a00, w10, acc10, 0, 0, 0);
        acc11 = __builtin_amdgcn_mfma_f32_16x16x32_bf16(a01, w10, acc11, 0, 0, 0);
        acc00 = __builtin_amdgcn_mfma_f32_16x16x32_bf16(a10, w01, acc00, 0, 0, 0);
        acc01 = __builtin_amdgcn_mfma_f32_16x16x32_bf16(a11, w01, acc01, 0, 0, 0);
        acc10 = __builtin_amdgcn_mfma_f32_16x16x32_bf16(a10, w11, acc10, 0, 0, 0);
        acc11 = __builtin_amdgcn_mfma_f32_16x16x32_bf16(a11, w11, acc11, 0, 0, 0);
    };

    GD gA, gB;
    LOADG(gA, 0);
    LOADG(gB, 1);
#pragma unroll
    for (int gl = 0; gl < GPW; gl += 2) {
        COMPUTE(gA, gl);     LOADG(gA, gl + 2);
        COMPUTE(gB, gl + 1); LOADG(gB, gl + 3);
    }

    // ---- inner-kseg reduction through LDS ----
    if (ks == 1) {
#pragma unroll
        for (int e = 0; e < 4; ++e) {
            red[cw][lane][e]      = acc00[e];
            red[cw][lane][4 + e]  = acc01[e];
            red[cw][lane][8 + e]  = acc10[e];
            red[cw][lane][12 + e] = acc11[e];
        }
    }
    __syncthreads();
    if (ks == 0) {
#pragma unroll
        for (int e = 0; e < 4; ++e) {
            acc00[e] += red[cw][lane][e];
            acc01[e] += red[cw][lane][4 + e];
            acc10[e] += red[cw][lane][8 + e];
            acc11[e] += red[cw][lane][12 + e];
        }
        // D layout (verified m89/m91): col = lane&15, row = (lane>>4)*4 + r
        float* pb = partial + (size_t)ob * PART_ELEMS;
#pragma unroll
        for (int r = 0; r < 4; ++r) {
            const int t = kg * 4 + r;
            pb[t * NDIM + n0]             = acc00[r];
            pb[(t + 16) * NDIM + n0]      = acc01[r];
            pb[t * NDIM + n0 + 16]        = acc10[r];
            pb[(t + 16) * NDIM + n0 + 16] = acc11[r];
        }
    }
}

// Epilogue: out = sum(partials) + bias.  88064 f32x4 slots, grid 344 x 256.
__global__ __launch_bounds__(256) void awq_epi(
    const float* __restrict__ part, const float* __restrict__ bias,
    float* __restrict__ out) {
    const int i = blockIdx.x * 256 + threadIdx.x;    // f32x4 slot, exact fit
    const f32x4* p = reinterpret_cast<const f32x4*>(part);
    f32x4 v = p[i];
#pragma unroll
    for (int o = 1; o < OUTK; ++o) v += p[(size_t)o * (PART_ELEMS / 4) + i];
    v += reinterpret_cast<const f32x4*>(bias)[i % (NDIM / 4)];
    reinterpret_cast<f32x4*>(out)[i] = v;
}

// Fallback (ws too small): round-7 kernel, f32-x path, no ws usage.
__global__ __launch_bounds__(256, 3) void awq_gemm_fb(
    const int* __restrict__ qw, const float* __restrict__ sc,
    const float* __restrict__ zp, const float* __restrict__ bias,
    const float* __restrict__ xf, float* __restrict__ out) {
    const int lane = threadIdx.x & 63;
    const int kseg = threadIdx.x >> 6;
    const int col  = lane & 15;
    const int kg   = lane >> 4;
    const int n    = blockIdx.x * 16 + col;
    const int sh0  = 8 * (n & 3);
    const int* qp  = qw + (n >> 2) * KP + kg * 4;
    const int r0 = col, r1 = col + 16;

    f32x4 acc0 = {0,0,0,0}, acc1 = {0,0,0,0};

    auto cvt8 = [](const float* p) {
        f32x4 u0 = *reinterpret_cast<const f32x4*>(p);
        f32x4 u1 = *reinterpret_cast<const f32x4*>(p + 4);
        s16x8 o;
#pragma unroll
        for (int e = 0; e < 4; ++e) {
            o[e]     = __builtin_bit_cast(short, __float2bfloat16(u0[e]));
            o[e + 4] = __builtin_bit_cast(short, __float2bfloat16(u1[e]));
        }
        return o;
    };

    const int g_lo = kseg * (NGRP / 4), g_hi = g_lo + (NGRP / 4);
#pragma unroll 2
    for (int g = g_lo; g < g_hi; ++g) {
        const float s = sc[g * NDIM + n];
        const float bz = -zp[g * NDIM + n] * s;
#pragma unroll
        for (int h = 0; h < 2; ++h) {
            const int chunk = 2 * g + h;
            i32x4 q = *reinterpret_cast<const i32x4*>(qp + chunk * 16);
            const float* p0 = xf + r0 * KDIM + chunk * 32 + kg * 8;
            const float* p1 = xf + r1 * KDIM + chunk * 32 + kg * 8;
            s16x8 a0 = cvt8(p0), a1 = cvt8(p1);
            s16x8 wf;
#pragma unroll
            for (int dd = 0; dd < 4; ++dd) {
                const int qd = q[dd];
                float w0 = (float)((qd >> sh0) & 15) * s + bz;
                float w1 = (float)((qd >> (sh0 + 4)) & 15) * s + bz;
                wf[2 * dd]     = __builtin_bit_cast(short, __float2bfloat16(w0));
                wf[2 * dd + 1] = __builtin_bit_cast(short, __float2bfloat16(w1));
            }
            acc0 = __builtin_amdgcn_mfma_f32_16x16x32_bf16(a0, wf, acc0, 0, 0, 0);
            acc1 = __builtin_amdgcn_mfma_f32_16x16x32_bf16(a1, wf, acc1, 0, 0, 0);
        }
    }

    __shared__ float red[3][64][9];
    if (kseg != 0) {
#pragma unroll
        for (int e = 0; e < 4; ++e) {
            red[kseg - 1][lane][e]     = acc0[e];
            red[kseg - 1][lane][4 + e] = acc1[e];
        }
    }
    __syncthreads();
    if (kseg == 0) {
#pragma unroll
        for (int ss = 0; ss < 3; ++ss)
#pragma unroll
            for (int e = 0; e < 4; ++e) {
                acc0[e] += red[ss][lane][e];
                acc1[e] += red[ss][lane][4 + e];
            }
        const float bv = bias[n];
#pragma unroll
        for (int r = 0; r < 4; ++r) {
            const int t = kg * 4 + r;
            out[t * NDIM + n]        = acc0[r] + bv;
            out[(t + 16) * NDIM + n] = acc1[r] + bv;
        }
    }
}

extern "C" void kernel_launch(void* const* d_in, const int* in_sizes, int n_in,
                              void* d_out, int out_size, void* d_ws, size_t ws_size,
                              hipStream_t stream) {
    const float* x    = (const float*)d_in[0];
    const int*   qw   = (const int*)d_in[1];
    const float* sc   = (const float*)d_in[2];
    const float* zp   = (const float*)d_in[3];
    const float* bias = (const float*)d_in[4];
    float*       out  = (float*)d_out;

    const size_t xb_bytes   = (size_t)TOKENS * KDIM * sizeof(unsigned short); // 256 KB
    const size_t part_bytes = (size_t)OUTK * PART_ELEMS * sizeof(float);      // ~11.3 MB

    if (ws_size >= xb_bytes + part_bytes) {
        unsigned short* xb = (unsigned short*)d_ws;
        float* part = (float*)((char*)d_ws + xb_bytes);
        cvt_x_kernel<<<64, 256, 0, stream>>>(x, (s16x8*)xb);
        awq_gemm2<<<NBLK_C * OUTK, 512, 0, stream>>>(qw, sc, zp, xb, part);
        awq_epi<<<(PART_ELEMS / 4) / 256, 256, 0, stream>>>(part, bias, out);
    } else {
        awq_gemm_fb<<<NDIM / 16, 256, 0, stream>>>(qw, sc, zp, bias, x, out);
    }
}

// Round 10
// 21.069 us; speedup vs baseline: 2.1883x; 1.2074x over previous
//
#include <hip/hip_runtime.h>
#include <hip/hip_bf16.h>

#define TOKENS 32
#define KDIM   4096
#define NDIM   11008
#define GSZ    64
#define KP     (KDIM/2)          // qweight row length in int32 (2048)
#define NGRP   (KDIM/GSZ)        // 64 groups
#define OUTK   8                 // K-splits across blocks (== 8 XCDs)
#define BLK_COLS 128             // 4 colWaves * 32 cols
#define NBLK_C (NDIM/BLK_COLS)   // 86
#define KSLICE (KDIM/OUTK)       // 512 k per block
#define GPW    (KSLICE/2/GSZ)    // 4 groups per wave (2 inner ksegs)
#define PART_ELEMS (TOKENS*NDIM) // 352256

typedef float  f32x4 __attribute__((ext_vector_type(4)));
typedef int    i32x4 __attribute__((ext_vector_type(4)));
typedef short  s16x8 __attribute__((ext_vector_type(8)));

// Main GEMM: grid = 688 blocks, 512 thr = 8 waves.
// ob = blockIdx % 8  -> one outer-kseg per XCD (round-robin dispatch): x slice,
// sc/zp rows, and partial[ob] all XCD-local; qweight slice 2.8MB fits L2.
// Wave = (colWave cw 0..3: 32 cols via 2 B-frags) x (inner kseg ks 0..1).
// Block stages its x K-slice (32 tok x 512 k) from f32, converting to bf16
// inline, into XOR-swizzled LDS (byte lin ^ ((tok&7)<<4)); a-frag reads apply
// the same xor to the full in-row offset.
// Dequant EXACT: (float)((q>>sh)&15)*s + (-z*s)  (magic-offset fails absmax).
// Inner ksegs reduced via LDS (buffer unioned with xs); f32 partials to ws.
__global__ __launch_bounds__(512, 2) void awq_gemm2(
    const int* __restrict__ qw, const float* __restrict__ sc,
    const float* __restrict__ zp, const float* __restrict__ xf,
    float* __restrict__ partial) {
    __shared__ unsigned short xs[TOKENS * KSLICE];   // 32 KB (reused for reduce)

    const int tid  = threadIdx.x;
    const int lane = tid & 63;
    const int wid  = tid >> 6;       // 0..7
    const int cw   = wid & 3;        // colWave
    const int ks   = wid >> 2;       // inner kseg 0..1
    const int ob   = blockIdx.x & 7;         // outer kseg == XCD
    const int bc   = blockIdx.x >> 3;        // col group 0..85
    const int K0   = ob * KSLICE;

    // ---- stage x slice: f32 global -> bf16 swizzled LDS (wave w: token it*8+w) ----
#pragma unroll
    for (int it = 0; it < 4; ++it) {
        const int lin  = it * 8192 + tid * 16;       // byte offset in bf16 slice
        const int tok  = lin >> 10;
        const int kloc = (lin & 1023) >> 1;          // = lane*8
        const float* xp = xf + tok * KDIM + K0 + kloc;
        f32x4 u0 = *reinterpret_cast<const f32x4*>(xp);
        f32x4 u1 = *reinterpret_cast<const f32x4*>(xp + 4);
        s16x8 v;
#pragma unroll
        for (int e = 0; e < 4; ++e) {
            v[e]     = __builtin_bit_cast(short, __float2bfloat16(u0[e]));
            v[e + 4] = __builtin_bit_cast(short, __float2bfloat16(u1[e]));
        }
        *reinterpret_cast<s16x8*>(
            reinterpret_cast<char*>(xs) + (lin ^ ((tok & 7) << 4))) = v;
    }
    __syncthreads();

    const int col  = lane & 15;
    const int kg   = lane >> 4;                      // k-subgroup 0..3
    const int n0   = bc * BLK_COLS + cw * 32 + col;  // colset-0 column
    const int sh0  = 8 * (n0 & 3);
    const int* qp0 = qw + (n0 >> 2) * KP + kg * 4;   // colset-1 = +4*KP ints

    f32x4 acc00 = {0,0,0,0}, acc01 = {0,0,0,0};      // [colset][Mtile]
    f32x4 acc10 = {0,0,0,0}, acc11 = {0,0,0,0};

    struct GD { float s0, z0, s1, z1; i32x4 qa0, qa1, qb0, qb1; };

    auto LOADG = [&](GD& d, int gl) {
        gl = gl < GPW ? gl : GPW - 1;                // clamp prefetch overhang
        const int gg = ob * (NGRP / OUTK) + ks * GPW + gl;  // global group
        d.s0 = sc[gg * NDIM + n0];        d.z0 = zp[gg * NDIM + n0];
        d.s1 = sc[gg * NDIM + n0 + 16];   d.z1 = zp[gg * NDIM + n0 + 16];
        const int* q = qp0 + gg * 32;
        d.qa0 = *reinterpret_cast<const i32x4*>(q);
        d.qa1 = *reinterpret_cast<const i32x4*>(q + 16);
        d.qb0 = *reinterpret_cast<const i32x4*>(q + 4 * KP);
        d.qb1 = *reinterpret_cast<const i32x4*>(q + 4 * KP + 16);
    };

    auto LDSA = [&](int tok, int c) -> s16x8 {       // a-frag from swizzled LDS
        const int inrow = ((c << 6) + (kg << 4)) ^ ((tok & 7) << 4);
        return *reinterpret_cast<const s16x8*>(
            reinterpret_cast<const char*>(xs) + (tok << 10) + inrow);
    };

    auto DQ = [&](const i32x4& q, float s, float bz) -> s16x8 {
        s16x8 wf;
#pragma unroll
        for (int dd = 0; dd < 4; ++dd) {
            const int qd = q[dd];
            float w0 = (float)((qd >> sh0) & 15) * s + bz;        // exact dequant
            float w1 = (float)((qd >> (sh0 + 4)) & 15) * s + bz;
            wf[2 * dd]     = __builtin_bit_cast(short, __float2bfloat16(w0));
            wf[2 * dd + 1] = __builtin_bit_cast(short, __float2bfloat16(w1));
        }
        return wf;
    };

    auto COMPUTE = [&](const GD& d, int gl) {
        const int c0 = ks * 8 + gl * 2;              // local K32-chunk
        s16x8 a00 = LDSA(col, c0),      a01 = LDSA(col + 16, c0);
        s16x8 a10 = LDSA(col, c0 + 1),  a11 = LDSA(col + 16, c0 + 1);
        const float bz0 = -d.z0 * d.s0, bz1 = -d.z1 * d.s1;
        s16x8 w00 = DQ(d.qa0, d.s0, bz0), w01 = DQ(d.qa1, d.s0, bz0);
        s16x8 w10 = DQ(d.qb0, d.s1, bz1), w11 = DQ(d.qb1, d.s1, bz1);
        acc00 = __builtin_amdgcn_mfma_f32_16x16x32_bf16(a00, w00, acc00, 0, 0, 0);
        acc01 = __builtin_amdgcn_mfma_f32_16x16x32_bf16(a01, w00, acc01, 0, 0, 0);
        acc10 = __builtin_amdgcn_mfma_f32_16x16x32_bf16(a00, w10, acc10, 0, 0, 0);
        acc11 = __builtin_amdgcn_mfma_f32_16x16x32_bf16(a01, w10, acc11, 0, 0, 0);
        acc00 = __builtin_amdgcn_mfma_f32_16x16x32_bf16(a10, w01, acc00, 0, 0, 0);
        acc01 = __builtin_amdgcn_mfma_f32_16x16x32_bf16(a11, w01, acc01, 0, 0, 0);
        acc10 = __builtin_amdgcn_mfma_f32_16x16x32_bf16(a10, w11, acc10, 0, 0, 0);
        acc11 = __builtin_amdgcn_mfma_f32_16x16x32_bf16(a11, w11, acc11, 0, 0, 0);
    };

    GD gA, gB;
    LOADG(gA, 0);
    LOADG(gB, 1);
#pragma unroll
    for (int gl = 0; gl < GPW; gl += 2) {
        COMPUTE(gA, gl);     LOADG(gA, gl + 2);
        COMPUTE(gB, gl + 1); LOADG(gB, gl + 3);
    }

    // ---- inner-kseg reduction through LDS (reuse xs; done reading a-frags) ----
    __syncthreads();
    float (*red)[64][17] = reinterpret_cast<float (*)[64][17]>(xs);  // 17.4KB<32KB
    if (ks == 1) {
#pragma unroll
        for (int e = 0; e < 4; ++e) {
            red[cw][lane][e]      = acc00[e];
            red[cw][lane][4 + e]  = acc01[e];
            red[cw][lane][8 + e]  = acc10[e];
            red[cw][lane][12 + e] = acc11[e];
        }
    }
    __syncthreads();
    if (ks == 0) {
#pragma unroll
        for (int e = 0; e < 4; ++e) {
            acc00[e] += red[cw][lane][e];
            acc01[e] += red[cw][lane][4 + e];
            acc10[e] += red[cw][lane][8 + e];
            acc11[e] += red[cw][lane][12 + e];
        }
        // D layout (verified m89/m91): col = lane&15, row = (lane>>4)*4 + r
        float* pb = partial + (size_t)ob * PART_ELEMS;
#pragma unroll
        for (int r = 0; r < 4; ++r) {
            const int t = kg * 4 + r;
            pb[t * NDIM + n0]             = acc00[r];
            pb[(t + 16) * NDIM + n0]      = acc01[r];
            pb[t * NDIM + n0 + 16]        = acc10[r];
            pb[(t + 16) * NDIM + n0 + 16] = acc11[r];
        }
    }
}

// Epilogue: out = sum(partials) + bias.  88064 f32x4 slots = 688 x 128.
__global__ __launch_bounds__(128) void awq_epi(
    const float* __restrict__ part, const float* __restrict__ bias,
    float* __restrict__ out) {
    const int i = blockIdx.x * 128 + threadIdx.x;    // f32x4 slot, exact fit
    const f32x4* p = reinterpret_cast<const f32x4*>(part);
    f32x4 v = p[i];
#pragma unroll
    for (int o = 1; o < OUTK; ++o) v += p[(size_t)o * (PART_ELEMS / 4) + i];
    v += reinterpret_cast<const f32x4*>(bias)[i % (NDIM / 4)];
    reinterpret_cast<f32x4*>(out)[i] = v;
}

// Fallback (ws too small): round-7 kernel, f32-x path, no ws usage.
__global__ __launch_bounds__(256, 3) void awq_gemm_fb(
    const int* __restrict__ qw, const float* __restrict__ sc,
    const float* __restrict__ zp, const float* __restrict__ bias,
    const float* __restrict__ xf, float* __restrict__ out) {
    const int lane = threadIdx.x & 63;
    const int kseg = threadIdx.x >> 6;
    const int col  = lane & 15;
    const int kg   = lane >> 4;
    const int n    = blockIdx.x * 16 + col;
    const int sh0  = 8 * (n & 3);
    const int* qp  = qw + (n >> 2) * KP + kg * 4;
    const int r0 = col, r1 = col + 16;

    f32x4 acc0 = {0,0,0,0}, acc1 = {0,0,0,0};

    auto cvt8 = [](const float* p) {
        f32x4 u0 = *reinterpret_cast<const f32x4*>(p);
        f32x4 u1 = *reinterpret_cast<const f32x4*>(p + 4);
        s16x8 o;
#pragma unroll
        for (int e = 0; e < 4; ++e) {
            o[e]     = __builtin_bit_cast(short, __float2bfloat16(u0[e]));
            o[e + 4] = __builtin_bit_cast(short, __float2bfloat16(u1[e]));
        }
        return o;
    };

    const int g_lo = kseg * (NGRP / 4), g_hi = g_lo + (NGRP / 4);
#pragma unroll 2
    for (int g = g_lo; g < g_hi; ++g) {
        const float s = sc[g * NDIM + n];
        const float bz = -zp[g * NDIM + n] * s;
#pragma unroll
        for (int h = 0; h < 2; ++h) {
            const int chunk = 2 * g + h;
            i32x4 q = *reinterpret_cast<const i32x4*>(qp + chunk * 16);
            const float* p0 = xf + r0 * KDIM + chunk * 32 + kg * 8;
            const float* p1 = xf + r1 * KDIM + chunk * 32 + kg * 8;
            s16x8 a0 = cvt8(p0), a1 = cvt8(p1);
            s16x8 wf;
#pragma unroll
            for (int dd = 0; dd < 4; ++dd) {
                const int qd = q[dd];
                float w0 = (float)((qd >> sh0) & 15) * s + bz;
                float w1 = (float)((qd >> (sh0 + 4)) & 15) * s + bz;
                wf[2 * dd]     = __builtin_bit_cast(short, __float2bfloat16(w0));
                wf[2 * dd + 1] = __builtin_bit_cast(short, __float2bfloat16(w1));
            }
            acc0 = __builtin_amdgcn_mfma_f32_16x16x32_bf16(a0, wf, acc0, 0, 0, 0);
            acc1 = __builtin_amdgcn_mfma_f32_16x16x32_bf16(a1, wf, acc1, 0, 0, 0);
        }
    }

    __shared__ float red[3][64][9];
    if (kseg != 0) {
#pragma unroll
        for (int e = 0; e < 4; ++e) {
            red[kseg - 1][lane][e]     = acc0[e];
            red[kseg - 1][lane][4 + e] = acc1[e];
        }
    }
    __syncthreads();
    if (kseg == 0) {
#pragma unroll
        for (int ss = 0; ss < 3; ++ss)
#pragma unroll
            for (int e = 0; e < 4; ++e) {
                acc0[e] += red[ss][lane][e];
                acc1[e] += red[ss][lane][4 + e];
            }
        const float bv = bias[n];
#pragma unroll
        for (int r = 0; r < 4; ++r) {
            const int t = kg * 4 + r;
            out[t * NDIM + n]        = acc0[r] + bv;
            out[(t + 16) * NDIM + n] = acc1[r] + bv;
        }
    }
}

extern "C" void kernel_launch(void* const* d_in, const int* in_sizes, int n_in,
                              void* d_out, int out_size, void* d_ws, size_t ws_size,
                              hipStream_t stream) {
    const float* x    = (const float*)d_in[0];
    const int*   qw   = (const int*)d_in[1];
    const float* sc   = (const float*)d_in[2];
    const float* zp   = (const float*)d_in[3];
    const float* bias = (const float*)d_in[4];
    float*       out  = (float*)d_out;

    const size_t part_bytes = (size_t)OUTK * PART_ELEMS * sizeof(float); // ~11.3 MB

    if (ws_size >= part_bytes) {
        float* part = (float*)d_ws;
        awq_gemm2<<<NBLK_C * OUTK, 512, 0, stream>>>(qw, sc, zp, x, part);
        awq_epi<<<PART_ELEMS / 4 / 128, 128, 0, stream>>>(part, bias, out);
    } else {
        awq_gemm_fb<<<NDIM / 16, 256, 0, stream>>>(qw, sc, zp, bias, x, out);
    }
}